// Round 1
// baseline (215.491 us; speedup 1.0000x reference)
//
#include <hip/hip_runtime.h>
#include <hip/hip_bf16.h>

// Problem constants
#define B_SZ 8
#define L_SZ 2048
#define DM   512
#define HIDC 1024            // complex hidden channels
#define NROW (B_SZ*L_SZ)     // 16384
#define NCOL (2*HIDC)        // 2048 (re || im)
#define LCH  128             // scan chunk length
#define NCH  (L_SZ/LCH)      // 16 chunks

typedef __attribute__((ext_vector_type(8))) short bf16x8;
typedef __attribute__((ext_vector_type(4))) float f32x4;

typedef __attribute__((address_space(1))) const void gvoid_t;
typedef __attribute__((address_space(3))) void lvoid_t;

__device__ __forceinline__ void gload_lds16(const void* g, void* l) {
  // async global->LDS, 16B per lane; LDS dest must be wave-uniform-base + lane*16
  __builtin_amdgcn_global_load_lds((gvoid_t*)g, (lvoid_t*)l, 16, 0, 0);
}

__device__ __forceinline__ unsigned short f2bf(float v) {
  return __builtin_bit_cast(unsigned short, __float2bfloat16(v));
}
__device__ __forceinline__ float bf2f(unsigned short u) {
  return __bfloat162float(__builtin_bit_cast(__hip_bfloat16, u));
}

// ---------------- prep kernels ----------------
__global__ void k_cvt_x(const float* __restrict__ x, unsigned short* __restrict__ xb) {
  long i = (long)blockIdx.x * 256 + threadIdx.x;   // 2,097,152 threads, 4 elems each
  float4 v = ((const float4*)x)[i];
  ushort4 o;
  o.x = f2bf(v.x); o.y = f2bf(v.y); o.z = f2bf(v.z); o.w = f2bf(v.w);
  ((ushort4*)xb)[i] = o;
}

// W1b[n][k], n<1024: gamma*W_in_r[n][k]; n>=1024: gamma*W_in_i[n-1024][k]. b1 = gamma*b.
__global__ void k_prep_w1(const float* __restrict__ Wr, const float* __restrict__ Wi,
                          const float* __restrict__ br, const float* __restrict__ bi,
                          const float* __restrict__ gamma_log,
                          unsigned short* __restrict__ W1b, float* __restrict__ b1) {
  long idx = (long)blockIdx.x * 256 + threadIdx.x; // 2048*512
  int n = (int)(idx >> 9), k = (int)(idx & 511);
  int d = n & (HIDC - 1);
  float g = __expf(gamma_log[d]);
  float w = (n < HIDC) ? Wr[(long)d * DM + k] : Wi[(long)d * DM + k];
  W1b[idx] = f2bf(g * w);
  if (k == 0) b1[n] = g * ((n < HIDC) ? br[d] : bi[d]);
}

// W2b[e][k], k<1024: W_out_r[e][k]; k>=1024: -W_out_i[e][k-1024]
__global__ void k_prep_w2(const float* __restrict__ Wor, const float* __restrict__ Woi,
                          unsigned short* __restrict__ W2b) {
  long idx = (long)blockIdx.x * 256 + threadIdx.x; // 512*2048
  int e = (int)(idx >> 11), k = (int)(idx & 2047);
  float w = (k < HIDC) ? Wor[(long)e * HIDC + k] : -Woi[(long)e * HIDC + (k - HIDC)];
  W2b[idx] = f2bf(w);
}

__global__ void k_prep_lam(const float* __restrict__ nu_log, const float* __restrict__ theta_log,
                           float* __restrict__ lam) {
  int d = blockIdx.x * 256 + threadIdx.x;   // 1024
  if (d >= HIDC) return;
  float nu = __expf(nu_log[d]);
  float th = __expf(theta_log[d]);
  float mag = __expf(-nu);
  lam[d]        = mag * cosf(th);
  lam[HIDC + d] = mag * sinf(th);
}

// ---------------- bf16 MFMA GEMM: C[M][N] = A[M][K] * Bw[N][K]^T (+bias[col]) (+resid) ----
// m97 structure: 128x128 tile, BK=32, 4 waves (2x2), 4x4 16x16x32 frags/wave,
// global_load_lds width 16, 2-barrier K loop.
template<int OUT_BF16, int HAS_RESID>
__global__ __launch_bounds__(256)
void gemm_bt(const unsigned short* __restrict__ A, const unsigned short* __restrict__ Bw,
             void* __restrict__ C, const float* __restrict__ bias,
             const float* __restrict__ resid, int M, int N, int K) {
  __shared__ unsigned short As[128 * 32];
  __shared__ unsigned short Bs[128 * 32];
  const int tid = threadIdx.x;
  const long m0 = (long)blockIdx.x * 128;
  const long n0 = (long)blockIdx.y * 128;
  const int w = tid >> 6, lane = tid & 63;
  const int wm = (w >> 1) * 64, wn = (w & 1) * 64;
  f32x4 acc[4][4] = {};

  // staging: thread tid loads 16B from row (tid>>2), col8 (tid&3)*8; two 64-row rounds
  const int srow = tid >> 2, scol = (tid & 3) * 8;
  const unsigned short* Ag = A + (m0 + srow) * (long)K + scol;
  const unsigned short* Bg = Bw + (n0 + srow) * (long)K + scol;
  unsigned short* Al = &As[srow * 32 + scol];
  unsigned short* Bl = &Bs[srow * 32 + scol];

  const int fr = lane & 15, fk = (lane >> 4) * 8;  // fragment row & k-offset

  for (int k0 = 0; k0 < K; k0 += 32) {
    __syncthreads();                                    // LDS consumed by all waves
    gload_lds16(Ag + k0, Al);
    gload_lds16(Ag + (long)64 * K + k0, Al + 64 * 32);
    gload_lds16(Bg + k0, Bl);
    gload_lds16(Bg + (long)64 * K + k0, Bl + 64 * 32);
    __syncthreads();                                    // compiler drains vmcnt before barrier
    bf16x8 fa[4], fb[4];
#pragma unroll
    for (int m = 0; m < 4; m++)
      fa[m] = *(const bf16x8*)&As[(wm + m * 16 + fr) * 32 + fk];
#pragma unroll
    for (int n = 0; n < 4; n++)
      fb[n] = *(const bf16x8*)&Bs[(wn + n * 16 + fr) * 32 + fk];
#pragma unroll
    for (int m = 0; m < 4; m++)
#pragma unroll
      for (int n = 0; n < 4; n++)
        acc[m][n] = __builtin_amdgcn_mfma_f32_16x16x32_bf16(fa[m], fb[n], acc[m][n], 0, 0, 0);
  }

  // epilogue: C/D layout col=lane&15, row=(lane>>4)*4+r (m89-verified)
  const int cr0 = (lane >> 4) * 4, cc = lane & 15;
#pragma unroll
  for (int m = 0; m < 4; m++) {
#pragma unroll
    for (int n = 0; n < 4; n++) {
      long col = n0 + wn + n * 16 + cc;
      float bv = bias[col];
#pragma unroll
      for (int r = 0; r < 4; r++) {
        long row = m0 + wm + m * 16 + cr0 + r;
        float v = acc[m][n][r] + bv;
        if (HAS_RESID) v += resid[row * (long)N + col];
        if (OUT_BF16)
          ((unsigned short*)C)[row * (long)N + col] = f2bf(v);
        else
          ((float*)C)[row * (long)N + col] = v;
      }
    }
  }
}

// ---------------- chunked scan (3 passes), in-place on ubuf (bf16) ----------------
// ubuf layout: [B*L][2048], cols 0..1023 = re, 1024..2047 = im.
// pass 1: per (b, chunk, 256-ch group), local scan -> end value E[b][c][ri][d]
__global__ void k_scan_local(const __hip_bfloat16* __restrict__ u,
                             const float* __restrict__ lam,
                             const float* __restrict__ mask,
                             float* __restrict__ E) {
  int b = blockIdx.x, c = blockIdx.y, dg = blockIdx.z, t = threadIdx.x;
  int d = dg * 256 + t;
  float lr = lam[d], li = lam[HIDC + d];
  float hr = 0.f, hi = 0.f;
  const __hip_bfloat16* ur = u + ((long)(b * L_SZ + c * LCH)) * NCOL + d;
  const __hip_bfloat16* ui = ur + HIDC;
  const float* mrow = mask + b * L_SZ + c * LCH;
  for (int l = 0; l < LCH; l++) {
    float xr = __bfloat162float(ur[(long)l * NCOL]);
    float xi = __bfloat162float(ui[(long)l * NCOL]);
    float g = (l > 0) ? mrow[l - 1] : 0.f;   // local carry starts at 0
    float nr = xr + g * (lr * hr - li * hi);
    float ni = xi + g * (lr * hi + li * hr);
    hr = nr; hi = ni;
  }
  E[(((long)b * NCH + c) * 2) * HIDC + d]     = hr;
  E[(((long)b * NCH + c) * 2 + 1) * HIDC + d] = hi;
}

// pass 2: scan chunk carries: P[c] = scan value at end of chunk c-1 (P[0]=0)
__global__ void k_scan_carry(const float* __restrict__ E, const float* __restrict__ lam,
                             float* __restrict__ P) {
  int idx = blockIdx.x * 256 + threadIdx.x;   // 8192 = B * HIDC
  int b = idx >> 10, d = idx & (HIDC - 1);
  float lr = lam[d], li = lam[HIDC + d];
  float ar = lr, ai = li;                     // lam^128 via 7 squarings
  for (int s = 0; s < 7; s++) { float nr = ar * ar - ai * ai; float ni = 2.f * ar * ai; ar = nr; ai = ni; }
  float pr = 0.f, pi = 0.f;
  for (int c = 0; c < NCH; c++) {
    P[(((long)b * NCH + c) * 2) * HIDC + d]     = pr;
    P[(((long)b * NCH + c) * 2 + 1) * HIDC + d] = pi;
    float er = E[(((long)b * NCH + c) * 2) * HIDC + d];
    float ei = E[(((long)b * NCH + c) * 2 + 1) * HIDC + d];
    float nr = er + ar * pr - ai * pi;
    float ni = ei + ar * pi + ai * pr;
    pr = nr; pi = ni;
  }
}

// pass 3: finalize with carry-in P, write h (bf16) in place over u
__global__ void k_scan_final(__hip_bfloat16* __restrict__ u,
                             const float* __restrict__ lam,
                             const float* __restrict__ mask,
                             const float* __restrict__ P) {
  int b = blockIdx.x, c = blockIdx.y, dg = blockIdx.z, t = threadIdx.x;
  int d = dg * 256 + t;
  float lr = lam[d], li = lam[HIDC + d];
  float hr = P[(((long)b * NCH + c) * 2) * HIDC + d];
  float hi = P[(((long)b * NCH + c) * 2 + 1) * HIDC + d];
  __hip_bfloat16* ur = u + ((long)(b * L_SZ + c * LCH)) * NCOL + d;
  __hip_bfloat16* ui = ur + HIDC;
  const float* mrow = mask + b * L_SZ + c * LCH;
  for (int l = 0; l < LCH; l++) {
    float xr = __bfloat162float(ur[(long)l * NCOL]);
    float xi = __bfloat162float(ui[(long)l * NCOL]);
    int gl = c * LCH + l;
    float g = (gl > 0) ? mrow[l - 1] : 0.f;  // mrow[-1] = prev chunk's last mask (valid for c>0)
    float nr = xr + g * (lr * hr - li * hi);
    float ni = xi + g * (lr * hi + li * hr);
    hr = nr; hi = ni;
    ur[(long)l * NCOL] = __float2bfloat16(hr);
    ui[(long)l * NCOL] = __float2bfloat16(hi);
  }
}

// ---------------- LayerNorm over D=512, in place on d_out ----------------
__global__ __launch_bounds__(256) void k_ln(float* __restrict__ y,
                                            const float* __restrict__ lnw,
                                            const float* __restrict__ lnb) {
  int row = blockIdx.x, t = threadIdx.x;
  float2 v = ((const float2*)(y + (long)row * DM))[t];
  float s = v.x + v.y;
  float q = v.x * v.x + v.y * v.y;
  for (int off = 32; off; off >>= 1) { s += __shfl_down(s, off); q += __shfl_down(q, off); }
  __shared__ float ss[4], sq[4];
  int w = t >> 6, lane = t & 63;
  if (lane == 0) { ss[w] = s; sq[w] = q; }
  __syncthreads();
  if (t == 0) {
    float S = ss[0] + ss[1] + ss[2] + ss[3];
    float Q = sq[0] + sq[1] + sq[2] + sq[3];
    float mu = S / (float)DM;
    float var = Q / (float)DM - mu * mu;
    ss[0] = mu; sq[0] = rsqrtf(var + 1e-5f);
  }
  __syncthreads();
  float mu = ss[0], rstd = sq[0];
  float2 o;
  o.x = (v.x - mu) * rstd * lnw[2 * t]     + lnb[2 * t];
  o.y = (v.y - mu) * rstd * lnw[2 * t + 1] + lnb[2 * t + 1];
  ((float2*)(y + (long)row * DM))[t] = o;
}

// ---------------- launch ----------------
extern "C" void kernel_launch(void* const* d_in, const int* in_sizes, int n_in,
                              void* d_out, int out_size, void* d_ws, size_t ws_size,
                              hipStream_t stream) {
  (void)in_sizes; (void)n_in; (void)out_size; (void)ws_size;
  const float* x         = (const float*)d_in[0];
  const float* mask      = (const float*)d_in[1];
  const float* nu_log    = (const float*)d_in[2];
  const float* theta_log = (const float*)d_in[3];
  const float* gamma_log = (const float*)d_in[4];
  const float* W_in_r    = (const float*)d_in[5];
  const float* W_in_i    = (const float*)d_in[6];
  const float* b_in_r    = (const float*)d_in[7];
  const float* b_in_i    = (const float*)d_in[8];
  const float* W_out_r   = (const float*)d_in[9];
  const float* W_out_i   = (const float*)d_in[10];
  const float* b_out_r   = (const float*)d_in[11];
  const float* ln_w      = (const float*)d_in[13];
  const float* ln_b      = (const float*)d_in[14];

  char* ws = (char*)d_ws;
  unsigned short* ubuf = (unsigned short*)(ws);              // 16384*2048*2 = 67,108,864
  unsigned short* xb   = (unsigned short*)(ws + 67108864);   // 16,777,216
  unsigned short* W1b  = (unsigned short*)(ws + 83886080);   // 2,097,152
  unsigned short* W2b  = (unsigned short*)(ws + 85983232);   // 2,097,152
  float* b1   = (float*)(ws + 88080384);                     // 8,192
  float* lam  = (float*)(ws + 88088576);                     // 8,192
  float* Ebuf = (float*)(ws + 88096768);                     // 1,048,576
  float* Pbuf = (float*)(ws + 89145344);                     // 1,048,576
  // total ws use: ~90.2 MB

  k_cvt_x  <<<8192, 256, 0, stream>>>(x, xb);
  k_prep_w1<<<4096, 256, 0, stream>>>(W_in_r, W_in_i, b_in_r, b_in_i, gamma_log, W1b, b1);
  k_prep_w2<<<4096, 256, 0, stream>>>(W_out_r, W_out_i, W2b);
  k_prep_lam<<<4, 256, 0, stream>>>(nu_log, theta_log, lam);

  // GEMM1: u = xb @ W1b^T + b1  -> bf16 ubuf [16384][2048]
  gemm_bt<1, 0><<<dim3(NROW / 128, NCOL / 128), 256, 0, stream>>>(
      xb, W1b, (void*)ubuf, b1, nullptr, NROW, NCOL, DM);

  // chunked linear-recurrence scan, in place on ubuf
  k_scan_local<<<dim3(B_SZ, NCH, HIDC / 256), 256, 0, stream>>>(
      (const __hip_bfloat16*)ubuf, lam, mask, Ebuf);
  k_scan_carry<<<32, 256, 0, stream>>>(Ebuf, lam, Pbuf);
  k_scan_final<<<dim3(B_SZ, NCH, HIDC / 256), 256, 0, stream>>>(
      (__hip_bfloat16*)ubuf, lam, mask, Pbuf);

  // GEMM2: out = h @ W2b^T + b_out_r + x  -> fp32 d_out [16384][512]
  gemm_bt<0, 1><<<dim3(NROW / 128, DM / 128), 256, 0, stream>>>(
      ubuf, W2b, d_out, b_out_r, x, NROW, DM, NCOL);

  // LayerNorm in place on d_out
  k_ln<<<NROW, 256, 0, stream>>>((float*)d_out, ln_w, ln_b);
}